// Round 22
// baseline (72.037 us; speedup 1.0000x reference)
//
#include <hip/hip_runtime.h>
#include <hip/hip_bf16.h>
#include <stdint.h>

// MHA B=1024,F=128,D=128,H=8,dh=16 fp32. Round 22: register diet to <=64
// VGPR (the m69 wave-slot quantum: 8 waves/SIMD only at VGPR<=64; R20 showed
// compiler targets 64 when unbounded but our body needed ~90 -> spill).
// (1) heads sequential + immediate per-head epilogue (predicated store on
//     hb==h; shfl for ones-column sum unpredicated) -> oA+oB 32 -> o 16 regs.
// (2) Ra -> LDS as packed bf16 pairs (stride 36B, all banks) -> -16 regs.
// (3) no launch_bounds: target 64 VGPR; LDS 34KB -> 4 blocks/CU -> 16 waves.
// Everything else from R21: ones-column sums, pk2t P-pack, exp2 builtin,
// setprio, swizzles, one barrier, 4096 blocks.

typedef __attribute__((ext_vector_type(8))) short short8;
typedef __attribute__((ext_vector_type(16))) float f32x16;
typedef __attribute__((ext_vector_type(4))) unsigned int uint4v;
typedef __attribute__((ext_vector_type(2))) unsigned int uint2v;
typedef unsigned short ushort_t;
typedef unsigned int uint_t;

#define KF_OFF 0        // Kfrag[2h][4tt][swizzled 1KiB]  (8 KiB)
#define QF_OFF 8192     // Qfrag[2h][4w][swizzled 1KiB]   (8 KiB)
#define VT_OFF 16384    // Vt[2h][16e][128f] bf16, e-swizzled (8 KiB)
#define ONES_OFF 24576  // 256 B of bf16 1.0 (sum column)
#define RA_OFF 24832    // Ra bf16 pairs [t*36 + r2*4], 9216 B
#define LDS_SZ 34048

__device__ __forceinline__ ushort_t b16(float f) {  // exact RNE (prep only)
  return __builtin_bit_cast(ushort_t, __float2bfloat16(f));
}
__device__ __forceinline__ uint_t rnd(float f) {  // round-nearest bits
  return __float_as_uint(f) + 0x8000u;
}
__device__ __forceinline__ uint_t pk2(float a, float b) {  // {lo:a, hi:b} RN
  return __byte_perm(rnd(a), rnd(b), 0x7632);
}
__device__ __forceinline__ uint_t pk2t(float a, float b) {  // truncating, 1 inst
  return __byte_perm(__float_as_uint(a), __float_as_uint(b), 0x7632);
}
__device__ __forceinline__ ushort_t b16d(float f) {  // device scalar, 2 inst
  return (ushort_t)(rnd(f) >> 16);
}

// ---- prep: weights fp32 -> bf16, 32x32x16 B-fragment order; cexp into Wq --
__global__ void prep_w(const float* __restrict__ Wq, const float* __restrict__ Wk,
                       const float* __restrict__ Wv, const float* __restrict__ Wr,
                       ushort_t* __restrict__ wt) {
  int i = blockIdx.x * 256 + threadIdx.x;  // 65536 total
  int u = i >> 9;
  int l = (i >> 3) & 63;
  int j = i & 7;
  int p = u >> 5, np = (u >> 3) & 3, kk = u & 7;
  int col = 32 * np + (l & 31);
  int d = kk * 16 + ((l >> 5) & 1) * 8 + j;
  const float* W = (p == 0) ? Wq : (p == 1) ? Wk : (p == 2) ? Wv : Wr;
  float scl = (p == 0) ? 0.12751459f : 1.0f;  // (1/sqrt(128))*log2(e) into Q
  wt[i] = b16(W[d * 128 + col] * scl);
}

// ---- main fused kernel -----------------------------------------------------
__global__ void mha22(const float* __restrict__ X,
                      const ushort_t* __restrict__ wt,
                      float* __restrict__ out) {
  __shared__ char lds[LDS_SZ];
  const int t = threadIdx.x;
  const int w = t >> 6, l = t & 63;
  const int i = blockIdx.x;
  const int b = (i & 7) * 128 + (i >> 5);   // XCD-sibling swizzle
  const int hq = (i >> 3) & 3;              // heads {2hq, 2hq+1}
  const int hi5 = l >> 5, q = l & 31, e = l & 15, hb = (l >> 4) & 1;

  // ones block for the sum column (written before the barrier)
  if (t < 16) {
    uint4v ones = {0x3F803F80u, 0x3F803F80u, 0x3F803F80u, 0x3F803F80u};
    *(uint4v*)(lds + ONES_OFF + t * 16) = ones;
  }

  // ---- A-fragments: wave's 32 X-rows direct from global, fp32 -> bf16 ----
  const float* xrow = X + (((size_t)b * 128) + 32 * w + q) * 128;
  short8 afr[8];
#pragma unroll
  for (int kk = 0; kk < 8; ++kk) {
    float4 a = *(const float4*)(xrow + kk * 16 + 8 * hi5);
    float4 c4 = *(const float4*)(xrow + kk * 16 + 8 * hi5 + 4);
    uint4v u = {pk2(a.x, a.y), pk2(a.z, a.w), pk2(c4.x, c4.y), pk2(c4.z, c4.w)};
    afr[kk] = __builtin_bit_cast(short8, u);
  }

  const short8* wf = (const short8*)wt;
  auto proj = [&](int p) {
    f32x16 acc = {};
#pragma unroll
    for (int kk = 0; kk < 8; ++kk) {
      short8 bfr = wf[((p * 4 + hq) * 8 + kk) * 64 + l];
      acc = __builtin_amdgcn_mfma_f32_32x32x16_bf16(afr[kk], bfr, acc, 0, 0, 0);
    }
    return acc;
  };
  // store D into fragment order with bank swizzle (R9-proven)
  auto st_qk = [&](int off, const f32x16& d) {
    const int uxor = ((e >> 3) | (hb << 1));
    char* p = lds + off + hb * 4096 + w * 1024 + 512 * (e >> 3) +
              (e & 7) * 2 + 64 * hi5;
#pragma unroll
    for (int r = 0; r < 16; ++r) {
      int u = (r & 3) + 8 * (r >> 2);
      *(ushort_t*)(p + 16 * (u ^ uxor)) = b16d(d[r]);
    }
  };
  auto st_v = [&](const f32x16& d) {  // transposed Vt[e][f], packed 8B
#pragma unroll
    for (int q2 = 0; q2 < 4; ++q2) {
      int f0 = 32 * w + 8 * q2 + 4 * hi5;
      uint2v pk = {pk2(d[4 * q2 + 0], d[4 * q2 + 1]),
                   pk2(d[4 * q2 + 2], d[4 * q2 + 3])};
      *(uint2v*)(lds + VT_OFF + hb * 4096 + e * 256 +
                 ((f0 * 2) ^ ((e & 7) << 4))) = pk;
    }
  };

  {
    f32x16 d;
    d = proj(0); st_qk(QF_OFF, d);   // Q (pre-scaled in weights)
    d = proj(1); st_qk(KF_OFF, d);
    d = proj(2); st_v(d);
    d = proj(3);                     // residual -> LDS bf16 pairs (private)
#pragma unroll
    for (int r2 = 0; r2 < 8; ++r2)
      *(uint_t*)(lds + RA_OFF + t * 36 + r2 * 4) = pk2(d[2 * r2], d[2 * r2 + 1]);
  }
  __syncthreads();  // only barrier

  // ---- attention: heads sequential; per-head immediate epilogue ----
#pragma unroll
  for (int h = 0; h < 2; ++h) {
    const int sw = (hi5 | (h << 1)) << 4;
    short8 qf = *(const short8*)(lds + QF_OFF + h * 4096 + w * 1024 +
                                 ((l * 16) ^ sw));
    // lane one past the used half reads the ones column (sum) instead of V
    const char* vb = (h == 0)
        ? ((q == 16) ? (lds + ONES_OFF) : (lds + VT_OFF))
        : ((q == 0) ? (lds + ONES_OFF) : (lds + VT_OFF + 4096));
    f32x16 o = {};
#pragma unroll
    for (int tt = 0; tt < 4; ++tt) {
      short8 kf = *(const short8*)(lds + KF_OFF + h * 4096 + tt * 1024 +
                                   ((l * 16) ^ sw));
      f32x16 z = {};
      __builtin_amdgcn_s_setprio(1);
      f32x16 s = __builtin_amdgcn_mfma_f32_32x32x16_bf16(kf, qf, z, 0, 0, 0);
      __builtin_amdgcn_s_setprio(0);
#pragma unroll
      for (int r = 0; r < 16; ++r) s[r] = __builtin_amdgcn_exp2f(s[r]);
#pragma unroll
      for (int gg = 0; gg < 2; ++gg) {
        int rb = gg * 8, g = 2 * tt + gg;
        uint_t wl  = pk2t(s[rb + 0], s[rb + 1]);
        uint_t wl2 = pk2t(s[rb + 2], s[rb + 3]);
        uint_t wh  = pk2t(s[rb + 4], s[rb + 5]);
        uint_t wh2 = pk2t(s[rb + 6], s[rb + 7]);
        uint2v r0 = __builtin_amdgcn_permlane32_swap(wl, wh, false, false);
        uint2v r1 = __builtin_amdgcn_permlane32_swap(wl2, wh2, false, false);
        uint4v pw = {r0[0], r1[0], r0[1], r1[1]};
        short8 pa = __builtin_bit_cast(short8, pw);
        short8 vfr = *(const short8*)(vb + e * 256 +
                                      ((32 * g + 16 * hi5) ^ ((e & 7) << 4)));
        __builtin_amdgcn_s_setprio(1);
        o = __builtin_amdgcn_mfma_f32_32x32x16_bf16(pa, vfr, o, 0, 0, 0);
        __builtin_amdgcn_s_setprio(0);
      }
    }
    // epilogue for this head: sums in the ones column at lane (l&32)|16 (h0)
    // or (l&32)|0 (h1), SAME reg index r. shfl unpredicated; store hb==h.
    const int srcl = (l & 32) | (h ? 0 : 16);
#pragma unroll
    for (int r2 = 0; r2 < 8; ++r2) {
      uint_t rap = *(const uint_t*)(lds + RA_OFF + t * 36 + r2 * 4);
#pragma unroll
      for (int j = 0; j < 2; ++j) {
        int r = 2 * r2 + j;
        float sv = __shfl(o[r], srcl, 64);
        float rsr = __builtin_amdgcn_rcpf(sv);
        float ra = __uint_as_float(j ? (rap & 0xffff0000u) : (rap << 16));
        float val = __builtin_fmaf(o[r], rsr, ra);
        int row = (r & 3) + 8 * (r >> 2) + 4 * hi5;
        if (hb == h)
          out[(((size_t)b * 128) + 32 * w + row) * 128 + 32 * hq + q] = val;
      }
    }
  }
}

extern "C" void kernel_launch(void* const* d_in, const int* in_sizes, int n_in,
                              void* d_out, int out_size, void* d_ws, size_t ws_size,
                              hipStream_t stream) {
  const float* X  = (const float*)d_in[0];
  const float* Wq = (const float*)d_in[1];
  const float* Wk = (const float*)d_in[2];
  const float* Wv = (const float*)d_in[3];
  const float* Wr = (const float*)d_in[4];
  float* out = (float*)d_out;
  ushort_t* wt = (ushort_t*)d_ws;  // 128 KiB fragment-ordered bf16 weights

  hipLaunchKernelGGL(prep_w, dim3(256), dim3(256), 0, stream, Wq, Wk, Wv, Wr, wt);
  hipLaunchKernelGGL(mha22, dim3(4096), dim3(256), 0, stream, X, wt, out);
}

// Round 23
// 62.116 us; speedup vs baseline: 1.1597x; 1.1597x over previous
//
#include <hip/hip_runtime.h>
#include <hip/hip_bf16.h>
#include <stdint.h>

// MHA B=1024,F=128,D=128,H=8,dh=16 fp32. Round 23: revert to R19 (62.5us,
// best; occupancy arc R20-R22 proved higher residency never pays here) and
// extend R18's proven truncation conversion to ALL sites: afr (X), st_v,
// st_qk (plain >>16, pattern-matches ds_write_b16_d16_hi). One-sided 2^-9
// error, output perturbation ~0.01 on 0.0656 budget. -64..80 VALU insts.
// No inline asm (R2/R4/R15 ledger). Everything else identical to R19.

typedef __attribute__((ext_vector_type(8))) short short8;
typedef __attribute__((ext_vector_type(16))) float f32x16;
typedef __attribute__((ext_vector_type(4))) unsigned int uint4v;
typedef __attribute__((ext_vector_type(2))) unsigned int uint2v;
typedef unsigned short ushort_t;
typedef unsigned int uint_t;

#define KF_OFF 0        // Kfrag[2h][4tt][swizzled 1KiB]  (8 KiB)
#define QF_OFF 8192     // Qfrag[2h][4w][swizzled 1KiB]   (8 KiB)
#define VT_OFF 16384    // Vt[2h][16e][128f] bf16, e-swizzled (8 KiB)
#define ONES_OFF 24576  // 256 B of bf16 1.0 (sum column)

__device__ __forceinline__ ushort_t b16(float f) {  // exact RNE (prep only)
  return __builtin_bit_cast(ushort_t, __float2bfloat16(f));
}
// truncating pack {lo: bf16t(a), hi: bf16t(b)} -- 1 VALU inst (v_perm_b32)
__device__ __forceinline__ uint_t pk2t(float a, float b) {
  return __byte_perm(__float_as_uint(a), __float_as_uint(b), 0x7632);
}
__device__ __forceinline__ ushort_t b16t(float f) {  // truncating scalar
  return (ushort_t)(__float_as_uint(f) >> 16);       // -> ds_write_b16_d16_hi
}

// ---- prep: weights fp32 -> bf16, 32x32x16 B-fragment order; cexp into Wq --
__global__ void prep_w(const float* __restrict__ Wq, const float* __restrict__ Wk,
                       const float* __restrict__ Wv, const float* __restrict__ Wr,
                       ushort_t* __restrict__ wt) {
  int i = blockIdx.x * 256 + threadIdx.x;  // 65536 total
  int u = i >> 9;
  int l = (i >> 3) & 63;
  int j = i & 7;
  int p = u >> 5, np = (u >> 3) & 3, kk = u & 7;
  int col = 32 * np + (l & 31);
  int d = kk * 16 + ((l >> 5) & 1) * 8 + j;
  const float* W = (p == 0) ? Wq : (p == 1) ? Wk : (p == 2) ? Wv : Wr;
  float scl = (p == 0) ? 0.12751459f : 1.0f;  // (1/sqrt(128))*log2(e) into Q
  wt[i] = b16(W[d * 128 + col] * scl);
}

// ---- main fused kernel -----------------------------------------------------
__global__ __launch_bounds__(256, 2) void mha23(const float* __restrict__ X,
                                                const ushort_t* __restrict__ wt,
                                                float* __restrict__ out) {
  __shared__ char lds[24832];
  const int t = threadIdx.x;
  const int w = t >> 6, l = t & 63;
  const int i = blockIdx.x;
  const int b = (i & 7) * 128 + (i >> 5);   // XCD-sibling swizzle
  const int hq = (i >> 3) & 3;              // heads {2hq, 2hq+1}
  const int hi5 = l >> 5, q = l & 31, e = l & 15, hb = (l >> 4) & 1;

  // ones block for the sum column (written before the barrier)
  if (t < 16) {
    uint4v ones = {0x3F803F80u, 0x3F803F80u, 0x3F803F80u, 0x3F803F80u};
    *(uint4v*)(lds + ONES_OFF + t * 16) = ones;
  }

  // ---- A-fragments: wave's 32 X-rows direct from global, fp32 -> bf16 ----
  const float* xrow = X + (((size_t)b * 128) + 32 * w + q) * 128;
  short8 afr[8];
#pragma unroll
  for (int kk = 0; kk < 8; ++kk) {
    float4 a = *(const float4*)(xrow + kk * 16 + 8 * hi5);
    float4 c4 = *(const float4*)(xrow + kk * 16 + 8 * hi5 + 4);
    uint4v u = {pk2t(a.x, a.y), pk2t(a.z, a.w), pk2t(c4.x, c4.y), pk2t(c4.z, c4.w)};
    afr[kk] = __builtin_bit_cast(short8, u);
  }

  const short8* wf = (const short8*)wt;
  auto proj = [&](int p) {
    f32x16 acc = {};
#pragma unroll
    for (int kk = 0; kk < 8; ++kk) {
      short8 bfr = wf[((p * 4 + hq) * 8 + kk) * 64 + l];
      acc = __builtin_amdgcn_mfma_f32_32x32x16_bf16(afr[kk], bfr, acc, 0, 0, 0);
    }
    return acc;
  };
  // store D into fragment order with bank swizzle (R9-proven)
  auto st_qk = [&](int off, const f32x16& d) {
    const int uxor = ((e >> 3) | (hb << 1));
    char* p = lds + off + hb * 4096 + w * 1024 + 512 * (e >> 3) +
              (e & 7) * 2 + 64 * hi5;
#pragma unroll
    for (int r = 0; r < 16; ++r) {
      int u = (r & 3) + 8 * (r >> 2);
      *(ushort_t*)(p + 16 * (u ^ uxor)) = b16t(d[r]);
    }
  };
  auto st_v = [&](const f32x16& d) {  // transposed Vt[e][f], packed 8B
#pragma unroll
    for (int q2 = 0; q2 < 4; ++q2) {
      int f0 = 32 * w + 8 * q2 + 4 * hi5;
      uint2v pk = {pk2t(d[4 * q2 + 0], d[4 * q2 + 1]),
                   pk2t(d[4 * q2 + 2], d[4 * q2 + 3])};
      *(uint2v*)(lds + VT_OFF + hb * 4096 + e * 256 +
                 ((f0 * 2) ^ ((e & 7) << 4))) = pk;
    }
  };

  f32x16 Ra;
  {
    f32x16 d;
    d = proj(0); st_qk(QF_OFF, d);   // Q (pre-scaled in weights)
    d = proj(1); st_qk(KF_OFF, d);
    d = proj(2); st_v(d);
    Ra = proj(3);
  }
  __syncthreads();  // only barrier

  // ---- attention: both heads interleaved per 32-key tile ----
  const int sw0 = hi5 << 4;         // read-side swizzle, head 0
  const int sw1 = (hi5 | 2) << 4;   // head 1
  short8 qf0 = *(const short8*)(lds + QF_OFF + w * 1024 + ((l * 16) ^ sw0));
  short8 qf1 = *(const short8*)(lds + QF_OFF + 4096 + w * 1024 +
                                ((l * 16) ^ sw1));
  // V base: the lane one past the used half reads the ones column instead
  // (its e is 0, so the swizzle term vanishes and addr = ONES_OFF+32g+16hi5)
  const char* vb0 = (q == 16) ? (lds + ONES_OFF) : (lds + VT_OFF);
  const char* vb1 = (q == 0) ? (lds + ONES_OFF) : (lds + VT_OFF + 4096);

  f32x16 oA = {}, oB = {};
  // softmax-finish + PV for one head's 32-key tile (truncating P pack)
  auto finish = [&](f32x16& s, f32x16& o, const char* vb, int tt) {
#pragma unroll
    for (int r = 0; r < 16; ++r) s[r] = __builtin_amdgcn_exp2f(s[r]);
#pragma unroll
    for (int gg = 0; gg < 2; ++gg) {
      int rb = gg * 8, g = 2 * tt + gg;
      uint_t wl  = pk2t(s[rb + 0], s[rb + 1]);
      uint_t wl2 = pk2t(s[rb + 2], s[rb + 3]);
      uint_t wh  = pk2t(s[rb + 4], s[rb + 5]);
      uint_t wh2 = pk2t(s[rb + 6], s[rb + 7]);
      uint2v r0 = __builtin_amdgcn_permlane32_swap(wl, wh, false, false);
      uint2v r1 = __builtin_amdgcn_permlane32_swap(wl2, wh2, false, false);
      uint4v pw = {r0[0], r1[0], r0[1], r1[1]};
      short8 pa = __builtin_bit_cast(short8, pw);
      short8 vfr = *(const short8*)(vb + e * 256 +
                                    ((32 * g + 16 * hi5) ^ ((e & 7) << 4)));
      __builtin_amdgcn_s_setprio(1);
      o = __builtin_amdgcn_mfma_f32_32x32x16_bf16(pa, vfr, o, 0, 0, 0);
      __builtin_amdgcn_s_setprio(0);
    }
  };

#pragma unroll
  for (int tt = 0; tt < 4; ++tt) {
    short8 kf0 = *(const short8*)(lds + KF_OFF + tt * 1024 + ((l * 16) ^ sw0));
    short8 kf1 = *(const short8*)(lds + KF_OFF + 4096 + tt * 1024 +
                                  ((l * 16) ^ sw1));
    f32x16 z0 = {}, z1 = {};
    __builtin_amdgcn_s_setprio(1);
    f32x16 s0 = __builtin_amdgcn_mfma_f32_32x32x16_bf16(kf0, qf0, z0, 0, 0, 0);
    f32x16 s1 = __builtin_amdgcn_mfma_f32_32x32x16_bf16(kf1, qf1, z1, 0, 0, 0);
    __builtin_amdgcn_s_setprio(0);
    finish(s0, oA, vb0, tt);   // h0 VALU chain overlaps h1's MFMA
    finish(s1, oB, vb1, tt);   // h1 VALU chain overlaps h0's PV MFMAs
  }

  // epilogue: per-row sums live in the ones columns (lane q==16 of oA,
  // lane q==0 of oB) at the SAME reg index r. Merge: d holds the sum value
  // on those lanes; one variable-lane shfl fetches own head's sum.
  const int srcl = (l & 32) | (hb ? 0 : 16);
#pragma unroll
  for (int r = 0; r < 16; ++r) {
    int row = (r & 3) + 8 * (r >> 2) + 4 * hi5;
    float d = (q == 16) ? oA[r] : oB[r];
    float s = __shfl(d, srcl, 64);
    float rsr = __builtin_amdgcn_rcpf(s);
    float ov = hb ? oB[r] : oA[r];
    float val = __builtin_fmaf(ov, rsr, Ra[r]);
    out[(((size_t)b * 128) + 32 * w + row) * 128 + 32 * hq + q] = val;
  }
}

extern "C" void kernel_launch(void* const* d_in, const int* in_sizes, int n_in,
                              void* d_out, int out_size, void* d_ws, size_t ws_size,
                              hipStream_t stream) {
  const float* X  = (const float*)d_in[0];
  const float* Wq = (const float*)d_in[1];
  const float* Wk = (const float*)d_in[2];
  const float* Wv = (const float*)d_in[3];
  const float* Wr = (const float*)d_in[4];
  float* out = (float*)d_out;
  ushort_t* wt = (ushort_t*)d_ws;  // 128 KiB fragment-ordered bf16 weights

  hipLaunchKernelGGL(prep_w, dim3(256), dim3(256), 0, stream, Wq, Wk, Wv, Wr, wt);
  hipLaunchKernelGGL(mha23, dim3(4096), dim3(256), 0, stream, X, wt, out);
}